// Round 14
// baseline (46.364 us; speedup 1.0000x reference)
//
#include <hip/hip_runtime.h>
#include <math.h>

// N=500000 points, M=128 centers, D=16.
#define M_CTR 128
#define D_DIM 16
#define KSTEPS 10          // K = 160 = 10 x 16
#define NSLOT 80           // phi slots per lane-half (80 x 2 = 160 = K)
#define GRID_MAIN 512      // 256-thr blocks, 4 indep waves -> 2048 waves
#define LOG2E 1.4426950408889634f
#define LN2   0.6931471805599453f

typedef _Float16 half8  __attribute__((ext_vector_type(8)));
typedef __fp16   fp16x2 __attribute__((ext_vector_type(2)));
typedef float   f32x16  __attribute__((ext_vector_type(16)));

// ---------------------------------------------------------------------------
// Slot table (see prior rounds): modes 0 = zs[a]*zs[b], 1 = zl[a]*zh[a],
// 2 = zs[a], 3 = pad; slot 76 = phi 1.0 carrying const_j/2 per lane-half.
// ---------------------------------------------------------------------------
struct SlotTab { unsigned char a[NSLOT]; unsigned char b[NSLOT]; unsigned char m[NSLOT]; };
constexpr SlotTab make_tab() {
    SlotTab T{};
    int s = 0;
    for (int d = 0; d < 8; ++d) { T.a[s] = (unsigned char)d; T.b[s] = (unsigned char)d; T.m[s] = 0; ++s; }
    for (int d = 0; d < 8; ++d)
        for (int f = d + 1; f < 8; ++f) { T.a[s] = (unsigned char)d; T.b[s] = (unsigned char)f; T.m[s] = 0; ++s; }
    for (int d = 0; d < 8; ++d)
        for (int f2 = d + 1; f2 < 8; ++f2) { T.a[s] = (unsigned char)d; T.b[s] = (unsigned char)(f2 + 8); T.m[s] = 0; ++s; }
    for (int d = 0; d < 4; ++d) { T.a[s] = (unsigned char)d; T.b[s] = (unsigned char)(d + 8); T.m[s] = 1; ++s; }
    for (int d = 0; d < 8; ++d) { T.a[s] = (unsigned char)d; T.b[s] = 0; T.m[s] = 2; ++s; }
    for (; s < NSLOT; ++s) { T.a[s] = 0; T.b[s] = 0; T.m[s] = 3; }
    return T;
}
constexpr SlotTab TAB = make_tab();

// ---------------------------------------------------------------------------
// Prep: one 64-thread block per center j (unchanged from prior rounds).
// ---------------------------------------------------------------------------
__global__ __launch_bounds__(64) void gmm_prep_kernel(
    const float* __restrict__ centers,   // [M,16]
    const float* __restrict__ Lmat,      // [M,16,16]
    const float* __restrict__ weights,   // [M]
    float* __restrict__ ws)
{
    const int j    = blockIdx.x;
    const int lane = threadIdx.x;        // 0..63
    const int r    = lane & 15;

    __shared__ float S_lds[D_DIM][D_DIM + 1];
    __shared__ float Scp_lds[D_DIM];

    float Lr[D_DIM];
    {
        const float4* Lrow = (const float4*)(Lmat + (size_t)j * 256 + r * 16);
        #pragma unroll
        for (int q = 0; q < 4; ++q) {
            const float4 v = Lrow[q];
            Lr[q * 4 + 0] = v.x; Lr[q * 4 + 1] = v.y;
            Lr[q * 4 + 2] = v.z; Lr[q * 4 + 3] = v.w;
        }
    }

    float u[D_DIM];
    #pragma unroll
    for (int e = 0; e < D_DIM; ++e) u[e] = Lr[e];
    float logdet = 0.f;
    #pragma unroll
    for (int k = 0; k < D_DIM; ++k) {
        const float pk = __shfl(u[k], k);
        logdet += logf(fabsf(pk));
        const float f = u[k] * (1.0f / pk);
        #pragma unroll
        for (int c = k + 1; c < D_DIM; ++c) {
            const float rkc = __shfl(u[c], k);
            if (r > k) u[c] -= f * rkc;
        }
    }

    #pragma unroll
    for (int f = 0; f < D_DIM; ++f) {
        float acc = 0.f;
        #pragma unroll
        for (int e = 0; e < D_DIM; ++e) acc += Lr[e] * __shfl(Lr[e], f);
        if (lane < D_DIM) S_lds[lane][f] = acc;
    }
    __syncthreads();

    float c[D_DIM];
    {
        const float4* cc = (const float4*)(centers + (size_t)j * D_DIM);
        #pragma unroll
        for (int q = 0; q < 4; ++q) {
            const float4 v = cc[q];
            c[q * 4 + 0] = v.x - 0.5f; c[q * 4 + 1] = v.y - 0.5f;
            c[q * 4 + 2] = v.z - 0.5f; c[q * 4 + 3] = v.w - 0.5f;
        }
    }
    if (lane < D_DIM) {
        float acc = 0.f;
        #pragma unroll
        for (int f = 0; f < D_DIM; ++f) acc += S_lds[lane][f] * c[f];
        Scp_lds[lane] = acc;
    }
    __syncthreads();
    float cSc = 0.f;
    #pragma unroll
    for (int d = 0; d < D_DIM; ++d) cSc += c[d] * Scp_lds[d];

    float wa = fabsf(weights[lane]) + fabsf(weights[lane + 64]);
    #pragma unroll
    for (int off = 32; off > 0; off >>= 1) wa += __shfl_xor(wa, off);
    const float lc = logf(fabsf(weights[j])) - logf(wa + 1e-30f) + logdet;
    const float cst_half = (lc - 0.5f * cSc) * 0.5f;

    if (lane < 2 * KSTEPS) {
        const int t  = lane >> 1;
        const int hi = lane & 1;
        const int mt = j >> 5;
        half8 hv;
        for (int e = 0; e < 8; ++e) {
            const int s  = t * 8 + e;
            const int mm = TAB.m[s], a = TAB.a[s], b = TAB.b[s];
            float val;
            if (mm == 0) {
                const int d = hi ? ((a + 8) & 15) : a;
                const int f = hi ? ((b + 8) & 15) : b;
                val = (d == f) ? -0.5f * S_lds[d][d] : -S_lds[d][f];
            } else if (mm == 1) {
                const int d = a + 4 * hi, f = a + 8 + 4 * hi;
                val = -S_lds[d][f];
            } else if (mm == 2) {
                val = Scp_lds[a + 8 * hi];
            } else {
                val = (s == 76) ? cst_half : 0.f;
            }
            hv[e] = (_Float16)(val * LOG2E);
        }
        char* dst = (char*)ws + (((mt * KSTEPS + t) * 64) + hi * 32 + (j & 31)) * 16;
        *(half8*)dst = hv;
    }
}

// full per-tile compute: load point, build phi, 40 MFMAs -> ACC0..ACC3
#define COMPUTE(ACC0, ACC1, ACC2, ACC3, TILE)                               \
    do {                                                                    \
        float z_[D_DIM];                                                    \
        {                                                                   \
            const float4* px_ = pbase + ((size_t)(TILE) * 32 + col) * 4;    \
            _Pragma("unroll")                                               \
            for (int q = 0; q < 4; ++q) {                                   \
                const float4 v_ = px_[q];                                   \
                z_[q * 4 + 0] = v_.x - 0.5f; z_[q * 4 + 1] = v_.y - 0.5f;   \
                z_[q * 4 + 2] = v_.z - 0.5f; z_[q * 4 + 3] = v_.w - 0.5f;   \
            }                                                               \
        }                                                                   \
        float zs_[16], zl_[4], zh_[4];                                      \
        _Pragma("unroll")                                                   \
        for (int i = 0; i < 16; ++i) zs_[i] = hi ? z_[(i + 8) & 15] : z_[i];\
        _Pragma("unroll")                                                   \
        for (int i = 0; i < 4; ++i) {                                       \
            zl_[i] = hi ? z_[i + 4]  : z_[i];                               \
            zh_[i] = hi ? z_[i + 12] : z_[i + 8];                           \
        }                                                                   \
        _Pragma("unroll")                                                   \
        for (int t = 0; t < KSTEPS; ++t) {                                  \
            float pv_[8];                                                   \
            _Pragma("unroll")                                               \
            for (int e = 0; e < 8; ++e) {                                   \
                const int s_  = t * 8 + e;                                  \
                const int mm_ = TAB.m[s_], a_ = TAB.a[s_], b_ = TAB.b[s_];  \
                pv_[e] = (mm_ == 0) ? zs_[a_] * zs_[b_]                     \
                       : (mm_ == 1) ? zl_[a_] * zh_[a_]                     \
                       : (mm_ == 2) ? zs_[a_]                               \
                       : ((s_ == 76) ? 1.0f : 0.0f);                        \
            }                                                               \
            union { half8 h8; fp16x2 h2[4]; } u_;                           \
            u_.h2[0] = __builtin_amdgcn_cvt_pkrtz(pv_[0], pv_[1]);          \
            u_.h2[1] = __builtin_amdgcn_cvt_pkrtz(pv_[2], pv_[3]);          \
            u_.h2[2] = __builtin_amdgcn_cvt_pkrtz(pv_[4], pv_[5]);          \
            u_.h2[3] = __builtin_amdgcn_cvt_pkrtz(pv_[6], pv_[7]);          \
            const half8 bf_ = u_.h8;                                        \
            const half8 a0_ = Ah[(0 * KSTEPS + t) * 64];                    \
            const half8 a1_ = Ah[(1 * KSTEPS + t) * 64];                    \
            const half8 a2_ = Ah[(2 * KSTEPS + t) * 64];                    \
            const half8 a3_ = Ah[(3 * KSTEPS + t) * 64];                    \
            if (t == 0) {                                                   \
                ACC0 = __builtin_amdgcn_mfma_f32_32x32x16_f16(a0_, bf_, ZV, 0, 0, 0); \
                ACC1 = __builtin_amdgcn_mfma_f32_32x32x16_f16(a1_, bf_, ZV, 0, 0, 0); \
                ACC2 = __builtin_amdgcn_mfma_f32_32x32x16_f16(a2_, bf_, ZV, 0, 0, 0); \
                ACC3 = __builtin_amdgcn_mfma_f32_32x32x16_f16(a3_, bf_, ZV, 0, 0, 0); \
            } else {                                                        \
                ACC0 = __builtin_amdgcn_mfma_f32_32x32x16_f16(a0_, bf_, ACC0, 0, 0, 0); \
                ACC1 = __builtin_amdgcn_mfma_f32_32x32x16_f16(a1_, bf_, ACC1, 0, 0, 0); \
                ACC2 = __builtin_amdgcn_mfma_f32_32x32x16_f16(a2_, bf_, ACC2, 0, 0, 0); \
                ACC3 = __builtin_amdgcn_mfma_f32_32x32x16_f16(a3_, bf_, ACC3, 0, 0, 0); \
            }                                                               \
        }                                                                   \
    } while (0)

// logsumexp epilogue over one tile's 4 accumulators -> out[TIDX*32+l]
#define EPILOGUE(ACC0, ACC1, ACC2, ACC3, TIDX)                              \
    do {                                                                    \
        float t0_[8];                                                       \
        _Pragma("unroll")                                                   \
        for (int i = 0; i < 8; ++i)                                         \
            t0_[i] = fmaxf(fmaxf(ACC0[i], ACC0[i + 8]),                     \
                           fmaxf(ACC1[i], ACC1[i + 8]));                    \
        _Pragma("unroll")                                                   \
        for (int i = 0; i < 8; ++i)                                         \
            t0_[i] = fmaxf(t0_[i], fmaxf(fmaxf(ACC2[i], ACC2[i + 8]),       \
                                         fmaxf(ACC3[i], ACC3[i + 8])));     \
        float m0_ = fmaxf(fmaxf(t0_[0], t0_[1]), fmaxf(t0_[2], t0_[3]));    \
        float m1_ = fmaxf(fmaxf(t0_[4], t0_[5]), fmaxf(t0_[6], t0_[7]));    \
        const float mx_ = fmaxf(m0_, m1_);                                  \
        float s0_ = 0.f, s1_ = 0.f, s2_ = 0.f, s3_ = 0.f;                   \
        _Pragma("unroll")                                                   \
        for (int rr = 0; rr < 16; ++rr) {                                   \
            s0_ += __builtin_amdgcn_exp2f(ACC0[rr] - mx_);                  \
            s1_ += __builtin_amdgcn_exp2f(ACC1[rr] - mx_);                  \
            s2_ += __builtin_amdgcn_exp2f(ACC2[rr] - mx_);                  \
            s3_ += __builtin_amdgcn_exp2f(ACC3[rr] - mx_);                  \
        }                                                                   \
        float ss_ = (s0_ + s1_) + (s2_ + s3_);                              \
        const float om_ = __shfl_xor(mx_, 32);                              \
        const float os_ = __shfl_xor(ss_, 32);                              \
        const float M2_ = fmaxf(mx_, om_);                                  \
        const float S2_ = ss_ * __builtin_amdgcn_exp2f(mx_ - M2_)           \
                        + os_ * __builtin_amdgcn_exp2f(om_ - M2_);          \
        if (l < 32)                                                         \
            out[(TIDX) * 32 + l] =                                          \
                fmaf(LN2, M2_ + __builtin_amdgcn_logf(S2_), -thrv);         \
    } while (0)

// ---------------------------------------------------------------------------
// Main: 256-thr blocks, 4 independent waves, ONE tile per iteration with a
// TWO-GENERATION accumulator ping-pong (T15 pattern): the iteration body is
// a single branch-free block [compute(C, next)] ; [epilogue(P, prev)] so the
// scheduler interleaves the epilogue's VALU/exp2 stream into the MFMA issue
// slots of the next tile. Loop unrolled x2 for static P/C naming.
// ---------------------------------------------------------------------------
__global__ __launch_bounds__(256) void gmm_main_kernel(
    const float* __restrict__ points,    // [N,16]
    const float* __restrict__ wsf,       // A-frags (40KB)
    const float* __restrict__ thr,       // [1]
    float* __restrict__ out,             // [N]
    int ntiles)
{
    __shared__ float4 A_lds4[2560];      // 40960 B

    const int tid = threadIdx.x;
    const int w   = tid >> 6;
    const int l   = tid & 63;
    const int col = l & 31;
    const bool hi = (l >> 5) != 0;

    {
        const float4* src = (const float4*)wsf;
        #pragma unroll
        for (int i = 0; i < 10; ++i)
            A_lds4[i * 256 + tid] = src[i * 256 + tid];
    }
    __syncthreads();                     // only barrier in the kernel

    const half8* Ah = (const half8*)A_lds4 + l;
    const float thrv = thr[0];
    const float4* pbase = (const float4*)points;

    const int wid    = blockIdx.x * 4 + w;
    const int stride = GRID_MAIN * 4;    // 2048 waves

    const f32x16 ZV = {0.f,0.f,0.f,0.f,0.f,0.f,0.f,0.f,
                       0.f,0.f,0.f,0.f,0.f,0.f,0.f,0.f};

    f32x16 aP0, aP1, aP2, aP3;           // previous generation (being finished)
    f32x16 aC0, aC1, aC2, aC3;           // current generation (being computed)

    int cur = wid;                       // tile whose acc lives in P
    if (cur >= ntiles) return;           // cannot happen (2048 < 15625), safety

    COMPUTE(aP0, aP1, aP2, aP3, cur);    // prologue: fill P

    int nxt = cur + stride;
    while (nxt < ntiles) {
        // ---- phase A: compute C(nxt) || finish P(cur) ----
        COMPUTE(aC0, aC1, aC2, aC3, nxt);
        EPILOGUE(aP0, aP1, aP2, aP3, cur);
        cur = nxt; nxt += stride;
        if (nxt >= ntiles) {
            EPILOGUE(aC0, aC1, aC2, aC3, cur);
            return;
        }
        // ---- phase B: compute P(nxt) || finish C(cur) ----
        COMPUTE(aP0, aP1, aP2, aP3, nxt);
        EPILOGUE(aC0, aC1, aC2, aC3, cur);
        cur = nxt; nxt += stride;
    }
    EPILOGUE(aP0, aP1, aP2, aP3, cur);   // drain
}

extern "C" void kernel_launch(void* const* d_in, const int* in_sizes, int n_in,
                              void* d_out, int out_size, void* d_ws, size_t ws_size,
                              hipStream_t stream) {
    const float* points  = (const float*)d_in[0];
    const float* centers = (const float*)d_in[1];
    const float* covs    = (const float*)d_in[2];
    const float* weights = (const float*)d_in[3];
    const float* thr     = (const float*)d_in[4];
    float* out = (float*)d_out;
    float* ws  = (float*)d_ws;

    const int n      = in_sizes[0] / D_DIM;   // 500000
    const int ntiles = n / 32;                // 15625 (exact)

    gmm_prep_kernel<<<M_CTR, 64, 0, stream>>>(centers, covs, weights, ws);
    gmm_main_kernel<<<GRID_MAIN, 256, 0, stream>>>(points, ws, thr, out, ntiles);
}

// Round 15
// 42.754 us; speedup vs baseline: 1.0844x; 1.0844x over previous
//
#include <hip/hip_runtime.h>
#include <math.h>

// N=500000 points, M=128 centers, D=16.
#define M_CTR 128
#define D_DIM 16
#define KSTEPS 10          // K = 160 = 10 x 16
#define NSLOT 80           // phi slots per lane-half (80 x 2 = 160 = K)
#define GRID_MAIN 256      // 512-thr blocks (8 waves) -> 2048 waves
#define LOG2E 1.4426950408889634f
#define LN2   0.6931471805599453f

typedef _Float16 half8  __attribute__((ext_vector_type(8)));
typedef __fp16   fp16x2 __attribute__((ext_vector_type(2)));
typedef float   f32x16  __attribute__((ext_vector_type(16)));

// ---------------------------------------------------------------------------
// Slot table: modes 0 = zs[a]*zs[b], 1 = zl[a]*zh[a], 2 = zs[a], 3 = pad;
// slot 76 = phi 1.0 carrying const_j/2 per lane-half. Lane-half hi gets the
// sigma(+8 mod 16) permutation baked into its LOAD addresses, so the same
// compile-time slot expressions serve both halves.
// ---------------------------------------------------------------------------
struct SlotTab { unsigned char a[NSLOT]; unsigned char b[NSLOT]; unsigned char m[NSLOT]; };
constexpr SlotTab make_tab() {
    SlotTab T{};
    int s = 0;
    for (int d = 0; d < 8; ++d) { T.a[s] = (unsigned char)d; T.b[s] = (unsigned char)d; T.m[s] = 0; ++s; }
    for (int d = 0; d < 8; ++d)
        for (int f = d + 1; f < 8; ++f) { T.a[s] = (unsigned char)d; T.b[s] = (unsigned char)f; T.m[s] = 0; ++s; }
    for (int d = 0; d < 8; ++d)
        for (int f2 = d + 1; f2 < 8; ++f2) { T.a[s] = (unsigned char)d; T.b[s] = (unsigned char)(f2 + 8); T.m[s] = 0; ++s; }
    for (int d = 0; d < 4; ++d) { T.a[s] = (unsigned char)d; T.b[s] = (unsigned char)(d + 8); T.m[s] = 1; ++s; }
    for (int d = 0; d < 8; ++d) { T.a[s] = (unsigned char)d; T.b[s] = 0; T.m[s] = 2; ++s; }
    for (; s < NSLOT; ++s) { T.a[s] = 0; T.b[s] = 0; T.m[s] = 3; }
    return T;
}
constexpr SlotTab TAB = make_tab();

// ---------------------------------------------------------------------------
// Prep: one 64-thread block per center j (unchanged; A layout identical).
// ---------------------------------------------------------------------------
__global__ __launch_bounds__(64) void gmm_prep_kernel(
    const float* __restrict__ centers,   // [M,16]
    const float* __restrict__ Lmat,      // [M,16,16]
    const float* __restrict__ weights,   // [M]
    float* __restrict__ ws)
{
    const int j    = blockIdx.x;
    const int lane = threadIdx.x;        // 0..63
    const int r    = lane & 15;

    __shared__ float S_lds[D_DIM][D_DIM + 1];
    __shared__ float Scp_lds[D_DIM];

    float Lr[D_DIM];
    {
        const float4* Lrow = (const float4*)(Lmat + (size_t)j * 256 + r * 16);
        #pragma unroll
        for (int q = 0; q < 4; ++q) {
            const float4 v = Lrow[q];
            Lr[q * 4 + 0] = v.x; Lr[q * 4 + 1] = v.y;
            Lr[q * 4 + 2] = v.z; Lr[q * 4 + 3] = v.w;
        }
    }

    float u[D_DIM];
    #pragma unroll
    for (int e = 0; e < D_DIM; ++e) u[e] = Lr[e];
    float logdet = 0.f;
    #pragma unroll
    for (int k = 0; k < D_DIM; ++k) {
        const float pk = __shfl(u[k], k);
        logdet += logf(fabsf(pk));
        const float f = u[k] * (1.0f / pk);
        #pragma unroll
        for (int c = k + 1; c < D_DIM; ++c) {
            const float rkc = __shfl(u[c], k);
            if (r > k) u[c] -= f * rkc;
        }
    }

    #pragma unroll
    for (int f = 0; f < D_DIM; ++f) {
        float acc = 0.f;
        #pragma unroll
        for (int e = 0; e < D_DIM; ++e) acc += Lr[e] * __shfl(Lr[e], f);
        if (lane < D_DIM) S_lds[lane][f] = acc;
    }
    __syncthreads();

    float c[D_DIM];
    {
        const float4* cc = (const float4*)(centers + (size_t)j * D_DIM);
        #pragma unroll
        for (int q = 0; q < 4; ++q) {
            const float4 v = cc[q];
            c[q * 4 + 0] = v.x - 0.5f; c[q * 4 + 1] = v.y - 0.5f;
            c[q * 4 + 2] = v.z - 0.5f; c[q * 4 + 3] = v.w - 0.5f;
        }
    }
    if (lane < D_DIM) {
        float acc = 0.f;
        #pragma unroll
        for (int f = 0; f < D_DIM; ++f) acc += S_lds[lane][f] * c[f];
        Scp_lds[lane] = acc;
    }
    __syncthreads();
    float cSc = 0.f;
    #pragma unroll
    for (int d = 0; d < D_DIM; ++d) cSc += c[d] * Scp_lds[d];

    float wa = fabsf(weights[lane]) + fabsf(weights[lane + 64]);
    #pragma unroll
    for (int off = 32; off > 0; off >>= 1) wa += __shfl_xor(wa, off);
    const float lc = logf(fabsf(weights[j])) - logf(wa + 1e-30f) + logdet;
    const float cst_half = (lc - 0.5f * cSc) * 0.5f;

    if (lane < 2 * KSTEPS) {
        const int t  = lane >> 1;
        const int hi = lane & 1;
        const int mt = j >> 5;
        half8 hv;
        for (int e = 0; e < 8; ++e) {
            const int s  = t * 8 + e;
            const int mm = TAB.m[s], a = TAB.a[s], b = TAB.b[s];
            float val;
            if (mm == 0) {
                const int d = hi ? ((a + 8) & 15) : a;
                const int f = hi ? ((b + 8) & 15) : b;
                val = (d == f) ? -0.5f * S_lds[d][d] : -S_lds[d][f];
            } else if (mm == 1) {
                const int d = a + 4 * hi, f = a + 8 + 4 * hi;
                val = -S_lds[d][f];
            } else if (mm == 2) {
                val = Scp_lds[a + 8 * hi];
            } else {
                val = (s == 76) ? cst_half : 0.f;
            }
            hv[e] = (_Float16)(val * LOG2E);
        }
        char* dst = (char*)ws + (((mt * KSTEPS + t) * 64) + hi * 32 + (j & 31)) * 16;
        *(half8*)dst = hv;
    }
}

// logsumexp epilogue over one tile's 4 accumulators -> out[TIDX*32+l]
#define EPILOGUE(ACC0, ACC1, ACC2, ACC3, TIDX)                              \
    do {                                                                    \
        float t0_[8];                                                       \
        _Pragma("unroll")                                                   \
        for (int i = 0; i < 8; ++i)                                         \
            t0_[i] = fmaxf(fmaxf(ACC0[i], ACC0[i + 8]),                     \
                           fmaxf(ACC1[i], ACC1[i + 8]));                    \
        _Pragma("unroll")                                                   \
        for (int i = 0; i < 8; ++i)                                         \
            t0_[i] = fmaxf(t0_[i], fmaxf(fmaxf(ACC2[i], ACC2[i + 8]),       \
                                         fmaxf(ACC3[i], ACC3[i + 8])));     \
        float m0_ = fmaxf(fmaxf(t0_[0], t0_[1]), fmaxf(t0_[2], t0_[3]));    \
        float m1_ = fmaxf(fmaxf(t0_[4], t0_[5]), fmaxf(t0_[6], t0_[7]));    \
        const float mx_ = fmaxf(m0_, m1_);                                  \
        float s0_ = 0.f, s1_ = 0.f, s2_ = 0.f, s3_ = 0.f;                   \
        _Pragma("unroll")                                                   \
        for (int rr = 0; rr < 16; ++rr) {                                   \
            s0_ += __builtin_amdgcn_exp2f(ACC0[rr] - mx_);                  \
            s1_ += __builtin_amdgcn_exp2f(ACC1[rr] - mx_);                  \
            s2_ += __builtin_amdgcn_exp2f(ACC2[rr] - mx_);                  \
            s3_ += __builtin_amdgcn_exp2f(ACC3[rr] - mx_);                  \
        }                                                                   \
        float ss_ = (s0_ + s1_) + (s2_ + s3_);                              \
        const float om_ = __shfl_xor(mx_, 32);                              \
        const float os_ = __shfl_xor(ss_, 32);                              \
        const float M2_ = fmaxf(mx_, om_);                                  \
        const float S2_ = ss_ * __builtin_amdgcn_exp2f(mx_ - M2_)           \
                        + os_ * __builtin_amdgcn_exp2f(om_ - M2_);          \
        if (l < 32)                                                         \
            out[(TIDX) * 32 + l] =                                          \
                fmaf(LN2, M2_ + __builtin_amdgcn_logf(S2_), -thrv);         \
    } while (0)

// ---------------------------------------------------------------------------
// Main (round 15): CODE-SIZE experiment. 512-thr blocks (8 waves sharing one
// 40KB A copy). Per tile: build all 10 B-frags (unrolled, ~160 instr), stage
// to a wave-PRIVATE LDS region (no barrier), then a ROLLED K-loop (5 ds_read
// + 4 MFMA per step, ~20 instr). Body shrinks ~2.5k -> ~0.5k instr to test
// the I-cache-thrash hypothesis for the redistribution-invariant 40us wall.
// Sigma permutation folded into load addresses (no zs cndmask).
// ---------------------------------------------------------------------------
__global__ __launch_bounds__(512) void gmm_main_kernel(
    const float* __restrict__ points,    // [N,16]
    const float* __restrict__ wsf,       // A-frags (40KB)
    const float* __restrict__ thr,       // [1]
    float* __restrict__ out,             // [N]
    int ntiles)
{
    __shared__ float4 ldsv[7680];        // 122880 B: A[0,40960) + B[40960,122880)

    const int tid = threadIdx.x;
    const int w   = tid >> 6;            // wave 0..7
    const int l   = tid & 63;
    const int col = l & 31;
    const bool hi = (l >> 5) != 0;

    // cooperative A fill: 2560 float4 / 512 threads = 5 each
    {
        const float4* src = (const float4*)wsf;
        #pragma unroll
        for (int i = 0; i < 5; ++i)
            ldsv[i * 512 + tid] = src[i * 512 + tid];
    }
    __syncthreads();                     // only barrier in the kernel

    const half8* Ah  = (const half8*)ldsv + l;              // + fb*64
    char*        Bb  = (char*)ldsv + 40960 + w * 10240 + l * 16;  // + t*1024
    const float  thrv = thr[0];
    const float4* pbase = (const float4*)points;

    const int wid    = blockIdx.x * 8 + w;
    const int stride = GRID_MAIN * 8;    // 2048 waves
    const int qoff   = hi ? 2 : 0;       // sigma(+8 mod 16) via quad rotation

    const f32x16 ZV = {0.f,0.f,0.f,0.f,0.f,0.f,0.f,0.f,
                       0.f,0.f,0.f,0.f,0.f,0.f,0.f,0.f};

    for (int tile = wid; tile < ntiles; tile += stride) {
        // permuted point load: zs[i] = x[sigma(i)] - 0.5 (sigma baked in addr)
        float zs[D_DIM];
        {
            const float4* px = pbase + ((size_t)tile * 32 + col) * 4;
            #pragma unroll
            for (int q = 0; q < 4; ++q) {
                const float4 v = px[(q + qoff) & 3];
                zs[q * 4 + 0] = v.x - 0.5f; zs[q * 4 + 1] = v.y - 0.5f;
                zs[q * 4 + 2] = v.z - 0.5f; zs[q * 4 + 3] = v.w - 0.5f;
            }
        }
        // mode-1 operands in permuted coordinates (8 cndmask)
        float zl[4], zh[4];
        #pragma unroll
        for (int i = 0; i < 4; ++i) {
            zl[i] = hi ? zs[i + 12] : zs[i];
            zh[i] = hi ? zs[i + 4]  : zs[i + 8];
        }

        // ---- build + stage all 10 B-frags (unrolled; wave-private region) ----
        #pragma unroll
        for (int t = 0; t < KSTEPS; ++t) {
            float pv[8];
            #pragma unroll
            for (int e = 0; e < 8; ++e) {
                const int s  = t * 8 + e;
                const int mm = TAB.m[s], a = TAB.a[s], b = TAB.b[s];
                pv[e] = (mm == 0) ? zs[a] * zs[b]
                      : (mm == 1) ? zl[a] * zh[a]
                      : (mm == 2) ? zs[a]
                      : ((s == 76) ? 1.0f : 0.0f);
            }
            union { half8 h8; fp16x2 h2[4]; } u;
            u.h2[0] = __builtin_amdgcn_cvt_pkrtz(pv[0], pv[1]);
            u.h2[1] = __builtin_amdgcn_cvt_pkrtz(pv[2], pv[3]);
            u.h2[2] = __builtin_amdgcn_cvt_pkrtz(pv[4], pv[5]);
            u.h2[3] = __builtin_amdgcn_cvt_pkrtz(pv[6], pv[7]);
            *(half8*)(Bb + t * 1024) = u.h8;
        }

        // ---- rolled K loop: tiny body -> fits I-cache ----
        f32x16 acc0, acc1, acc2, acc3;
        {   // peel t=0 (zero-C)
            const half8 bf = *(const half8*)(Bb + 0);
            acc0 = __builtin_amdgcn_mfma_f32_32x32x16_f16(Ah[(0 * KSTEPS) * 64], bf, ZV, 0, 0, 0);
            acc1 = __builtin_amdgcn_mfma_f32_32x32x16_f16(Ah[(1 * KSTEPS) * 64], bf, ZV, 0, 0, 0);
            acc2 = __builtin_amdgcn_mfma_f32_32x32x16_f16(Ah[(2 * KSTEPS) * 64], bf, ZV, 0, 0, 0);
            acc3 = __builtin_amdgcn_mfma_f32_32x32x16_f16(Ah[(3 * KSTEPS) * 64], bf, ZV, 0, 0, 0);
        }
        #pragma clang loop unroll(disable)
        for (int t = 1; t < KSTEPS; ++t) {
            const half8 bf = *(const half8*)(Bb + t * 1024);
            const half8 a0 = Ah[(0 * KSTEPS + t) * 64];
            const half8 a1 = Ah[(1 * KSTEPS + t) * 64];
            const half8 a2 = Ah[(2 * KSTEPS + t) * 64];
            const half8 a3 = Ah[(3 * KSTEPS + t) * 64];
            acc0 = __builtin_amdgcn_mfma_f32_32x32x16_f16(a0, bf, acc0, 0, 0, 0);
            acc1 = __builtin_amdgcn_mfma_f32_32x32x16_f16(a1, bf, acc1, 0, 0, 0);
            acc2 = __builtin_amdgcn_mfma_f32_32x32x16_f16(a2, bf, acc2, 0, 0, 0);
            acc3 = __builtin_amdgcn_mfma_f32_32x32x16_f16(a3, bf, acc3, 0, 0, 0);
        }

        EPILOGUE(acc0, acc1, acc2, acc3, tile);
    }
}

extern "C" void kernel_launch(void* const* d_in, const int* in_sizes, int n_in,
                              void* d_out, int out_size, void* d_ws, size_t ws_size,
                              hipStream_t stream) {
    const float* points  = (const float*)d_in[0];
    const float* centers = (const float*)d_in[1];
    const float* covs    = (const float*)d_in[2];
    const float* weights = (const float*)d_in[3];
    const float* thr     = (const float*)d_in[4];
    float* out = (float*)d_out;
    float* ws  = (float*)d_ws;

    const int n      = in_sizes[0] / D_DIM;   // 500000
    const int ntiles = n / 32;                // 15625 (exact)

    gmm_prep_kernel<<<M_CTR, 64, 0, stream>>>(centers, covs, weights, ws);
    gmm_main_kernel<<<GRID_MAIN, 512, 0, stream>>>(points, ws, thr, out, ntiles);
}